// Round 8
// baseline (575.028 us; speedup 1.0000x reference)
//
#include <hip/hip_runtime.h>
#include <hip/hip_bf16.h>

#define N_NODES  10000
#define N_EDGES  64000
#define N_GRAPHS 64
#define HID      64

typedef __attribute__((ext_vector_type(8))) short short8;
typedef __attribute__((ext_vector_type(4))) float f32x4;

__device__ __forceinline__ float lrelu(float v){ return v > 0.f ? v : 0.01f*v; }

__device__ __forceinline__ unsigned short f2bf(float f){
    union { float f; unsigned u; } v; v.f = f;
    unsigned r = v.u + 0x7fff + ((v.u >> 16) & 1);
    return (unsigned short)(r >> 16);
}
__device__ __forceinline__ float bf2f(unsigned short s){
    union { unsigned u; float f; } v; v.u = ((unsigned)s) << 16;
    return v.f;
}

// ---------------- preamble mega-kernel: nodeFC | w2conv(x2) | csr_count ----------------
#define PRE_NFC 2500
#define PRE_W2C 128
#define PRE_CNT 250
__global__ void __launch_bounds__(256) pre_kernel(
        const float* __restrict__ x, const float* __restrict__ nfc_w, const float* __restrict__ nfc_b,
        float* __restrict__ hx1,
        const float* __restrict__ e1w2, unsigned short* __restrict__ w2t1,
        const float* __restrict__ e2w2, unsigned short* __restrict__ w2t2,
        const int* __restrict__ src, int* __restrict__ counts){
    __shared__ float tile[64][65];
    int b = blockIdx.x, tid = threadIdx.x;
    if (b < PRE_NFC){
        int m = tid & 63, n = b * 4 + (tid >> 6);
        float acc = nfc_b[m];
        const float* row = x + (size_t)n * 128;
        #pragma unroll 8
        for (int k = 0; k < 128; ++k) acc += row[k] * nfc_w[k * 64 + m];
        hx1[(size_t)n * 64 + m] = lrelu(acc);
    } else if (b < PRE_NFC + PRE_W2C){
        int bb = b - PRE_NFC;
        int k = bb & 63;
        const float* srcw = ((bb < 64) ? e1w2 : e2w2) + (size_t)k * 4096;
        unsigned short* dstw = (bb < 64) ? w2t1 : w2t2;
        for (int idx = tid; idx < 4096; idx += 256) tile[idx >> 6][idx & 63] = srcw[idx];
        __syncthreads();
        for (int idx = tid; idx < 4096; idx += 256){
            int o = idx >> 6, i = idx & 63;
            dstw[((size_t)(k * 64 + o) << 6) + i] = f2bf(tile[i][o]);
        }
    } else {
        int e = (b - PRE_NFC - PRE_W2C) * 256 + tid;
        if (e < N_EDGES) atomicAdd(&counts[src[e]], 1);
    }
}

// scan rowptr from counts; also zero the scatter cursor
__global__ void csr_scan_kernel(const int* __restrict__ counts, int* __restrict__ rowptr,
                                int* __restrict__ cursor){
    __shared__ int part[256];
    int tid = threadIdx.x;
    const int CH = (N_NODES + 255) / 256;      // 40
    int base = tid * CH, s = 0;
    for (int i = 0; i < CH; ++i){ int idx = base + i; if (idx < N_NODES){ cursor[idx] = 0; s += counts[idx]; } }
    part[tid] = s; __syncthreads();
    for (int off = 1; off < 256; off <<= 1){
        int v = (tid >= off) ? part[tid - off] : 0;
        __syncthreads();
        part[tid] += v;
        __syncthreads();
    }
    int run = part[tid] - s;
    for (int i = 0; i < CH; ++i){ int idx = base + i; if (idx < N_NODES){ rowptr[idx] = run; run += counts[idx]; } }
    if (tid == 255) rowptr[N_NODES] = run;
}

__global__ void csr_scatter_kernel(const int* __restrict__ src, const int* __restrict__ dst,
                                   const int* __restrict__ rowptr, int* __restrict__ cursor,
                                   int* __restrict__ eidx, int* __restrict__ dsts){
    int e = blockIdx.x * 256 + threadIdx.x;
    if (e >= N_EDGES) return;
    int s = src[e];
    int j = rowptr[s] + atomicAdd(&cursor[s], 1);
    eidx[j] = e; dsts[j] = dst[e];
}

// ---------------- per-layer light kernel: t-GEMM(bf16, CSR order) | hb2 + agg-zero | (hg-zero) --
#define LB_NT 4000                 // 16 edges per block
#define LB_NH 625                  // 16 nodes per block
template<int L2FLAG>
__global__ void __launch_bounds__(256) layerB_kernel(
        const float* __restrict__ ea, const int* __restrict__ eidx,
        const float* __restrict__ w1, const float* __restrict__ b1, unsigned short* __restrict__ tp,
        const float* __restrict__ hx, const float* __restrict__ b2m,
        float* __restrict__ hb2, float* __restrict__ agg, float* __restrict__ hg){
    int b = blockIdx.x, tid = threadIdx.x;
    int m = tid & 63, y = tid >> 6;
    if (b < LB_NT){
        int j0 = b * 16 + y * 4;
        const float* r0 = ea + (size_t)eidx[j0 + 0] * 32;
        const float* r1 = ea + (size_t)eidx[j0 + 1] * 32;
        const float* r2 = ea + (size_t)eidx[j0 + 2] * 32;
        const float* r3 = ea + (size_t)eidx[j0 + 3] * 32;
        float bb = b1[m];
        float a0 = bb, a1 = bb, a2 = bb, a3 = bb;
        #pragma unroll
        for (int k = 0; k < 32; ++k){
            float wv = w1[k * 64 + m];
            a0 += r0[k] * wv; a1 += r1[k] * wv; a2 += r2[k] * wv; a3 += r3[k] * wv;
        }
        tp[((size_t)(j0 + 0) << 6) + m] = f2bf(fmaxf(a0, 0.f));
        tp[((size_t)(j0 + 1) << 6) + m] = f2bf(fmaxf(a1, 0.f));
        tp[((size_t)(j0 + 2) << 6) + m] = f2bf(fmaxf(a2, 0.f));
        tp[((size_t)(j0 + 3) << 6) + m] = f2bf(fmaxf(a3, 0.f));
    } else if (b < LB_NT + LB_NH){
        int n0 = (b - LB_NT) * 16 + y * 4;
        const float* r0 = hx + ((size_t)(n0 + 0) << 6);
        const float* r1 = hx + ((size_t)(n0 + 1) << 6);
        const float* r2 = hx + ((size_t)(n0 + 2) << 6);
        const float* r3 = hx + ((size_t)(n0 + 3) << 6);
        float a0 = 0.f, a1 = 0.f, a2 = 0.f, a3 = 0.f;
        #pragma unroll 8
        for (int k = 0; k < 64; ++k){
            float wv = b2m[k * 64 + m];
            a0 += r0[k] * wv; a1 += r1[k] * wv; a2 += r2[k] * wv; a3 += r3[k] * wv;
        }
        hb2[((size_t)(n0 + 0) << 6) + m] = a0;  agg[((size_t)(n0 + 0) << 6) + m] = 0.f;
        hb2[((size_t)(n0 + 1) << 6) + m] = a1;  agg[((size_t)(n0 + 1) << 6) + m] = 0.f;
        hb2[((size_t)(n0 + 2) << 6) + m] = a2;  agg[((size_t)(n0 + 2) << 6) + m] = 0.f;
        hb2[((size_t)(n0 + 3) << 6) + m] = a3;  agg[((size_t)(n0 + 3) << 6) + m] = 0.f;
    } else if (L2FLAG){
        for (int i = tid; i < N_GRAPHS * 64; i += 256) hg[i] = 0.f;
    }
}

// ---------------- fused gmat+msg: G tile lives ONLY in LDS, consumed in-place --------------
// Block (bx, by): nodes [bx*64, bx*64+64), k-slice [by*8, by*8+8) (cols cb..cb+512).
// Phase 1 (MFMA): stg[row][512 cols] bf16, XOR-swizzled. Phase 2: per-node edge loop,
// partial msg = sum_{kk} t[j, by*8+kk] * g[kk]; atomicAdd into agg[dst]. by==0 adds hb2[src].
#define FB_NBX 157
__global__ void __launch_bounds__(256) fused_gmat_msg_kernel(
        const float* __restrict__ hx, const unsigned short* __restrict__ w2t,
        const unsigned short* __restrict__ tp, const float* __restrict__ hb2,
        const int* __restrict__ rowptr, const int* __restrict__ dsts,
        float* __restrict__ agg){
    __shared__ unsigned short stg[64 * 512];   // 64 KB
    int tid = threadIdx.x;
    int wid = tid >> 6, l = tid & 63;
    int m16 = l & 15, grp = l >> 4;
    int n0 = blockIdx.x * 64;
    int cb = blockIdx.y * 512;

    // B fragments: 4 node-groups from global hx
    short8 bf0[4], bf1[4];
    #pragma unroll
    for (int ng = 0; ng < 4; ++ng){
        int node = n0 + ng * 16 + m16;
        short8 b0 = {0,0,0,0,0,0,0,0}, b1v = {0,0,0,0,0,0,0,0};
        if (node < N_NODES){
            const float* hp = hx + ((size_t)node << 6) + grp * 8;
            float4 f0 = *(const float4*)(hp);
            float4 f1 = *(const float4*)(hp + 4);
            float4 f2 = *(const float4*)(hp + 32);
            float4 f3 = *(const float4*)(hp + 36);
            b0[0]=(short)f2bf(f0.x); b0[1]=(short)f2bf(f0.y); b0[2]=(short)f2bf(f0.z); b0[3]=(short)f2bf(f0.w);
            b0[4]=(short)f2bf(f1.x); b0[5]=(short)f2bf(f1.y); b0[6]=(short)f2bf(f1.z); b0[7]=(short)f2bf(f1.w);
            b1v[0]=(short)f2bf(f2.x); b1v[1]=(short)f2bf(f2.y); b1v[2]=(short)f2bf(f2.z); b1v[3]=(short)f2bf(f2.w);
            b1v[4]=(short)f2bf(f3.x); b1v[5]=(short)f2bf(f3.y); b1v[6]=(short)f2bf(f3.z); b1v[7]=(short)f2bf(f3.w);
        }
        bf0[ng] = b0; bf1[ng] = b1v;
    }

    // Phase 1: 8 col-tiles x 4 node-groups of MFMA -> LDS (swizzled)
    #pragma unroll
    for (int t = 0; t < 8; ++t){
        int TB = cb + t * 64 + wid * 16;
        const unsigned short* ap = w2t + ((size_t)(TB + m16) << 6) + grp * 8;
        short8 a0 = *(const short8*)ap;
        short8 a1 = *(const short8*)(ap + 32);
        int colb = t * 128 + wid * 32 + grp * 8;          // byte offset within row
        #pragma unroll
        for (int ng = 0; ng < 4; ++ng){
            f32x4 acc = {0.f, 0.f, 0.f, 0.f};
            acc = __builtin_amdgcn_mfma_f32_16x16x32_bf16(a0, bf0[ng], acc, 0, 0, 0);
            acc = __builtin_amdgcn_mfma_f32_16x16x32_bf16(a1, bf1[ng], acc, 0, 0, 0);
            unsigned p0 = (unsigned)f2bf(acc[0]) | ((unsigned)f2bf(acc[1]) << 16);
            unsigned p1 = (unsigned)f2bf(acc[2]) | ((unsigned)f2bf(acc[3]) << 16);
            int row = ng * 16 + m16;
            int off = (row * 1024 + colb) ^ ((row & 7) << 4);
            uint2 pk; pk.x = p0; pk.y = p1;
            *(uint2*)((char*)stg + off) = pk;
        }
    }
    __syncthreads();

    // Phase 2: edge loop. wave wid owns rows [wid*16, wid*16+16); lane l = output col o.
    int hb_on = (blockIdx.y == 0);
    for (int rr = 0; rr < 16; ++rr){
        int row = wid * 16 + rr;
        int s = n0 + row;
        if (s >= N_NODES) break;
        int r0 = rowptr[s], r1 = rowptr[s + 1];
        if (r0 == r1) continue;
        float gk[8];
        #pragma unroll
        for (int kk = 0; kk < 8; ++kk){
            int off = (row * 1024 + kk * 128 + l * 2) ^ ((row & 7) << 4);
            gk[kk] = bf2f(*(const unsigned short*)((const char*)stg + off));
        }
        float hb = hb_on ? hb2[((size_t)s << 6) + l] : 0.f;
        for (int j = r0; j < r1; ++j){
            short8 tv = *(const short8*)(tp + ((size_t)j << 6) + (blockIdx.y << 3)); // uniform 16B
            float acc = hb;
            #pragma unroll
            for (int kk = 0; kk < 8; ++kk) acc += bf2f((unsigned short)tv[kk]) * gk[kk];
            atomicAdd(&agg[((size_t)dsts[j] << 6) + l], acc);
        }
    }
}

// out[n,o] = lrelu(agg[n,o] + hx[n] @ root + bias)
__global__ void combine_kernel(const float* __restrict__ agg, const float* __restrict__ hx,
                               const float* __restrict__ root, const float* __restrict__ bias,
                               float* __restrict__ out, int N){
    int m = threadIdx.x;
    int n = blockIdx.x * 4 + threadIdx.y;
    if (n >= N) return;
    float acc = agg[(size_t)n * 64 + m] + bias[m];
    const float* row = hx + (size_t)n * 64;
    #pragma unroll 8
    for (int k = 0; k < 64; ++k) acc += row[k] * root[k * 64 + m];
    out[(size_t)n * 64 + m] = lrelu(acc);
}

// layer-2 combine fused with global_add_pool
__global__ void combine2_kernel(const float* __restrict__ agg, const float* __restrict__ hx,
                                const float* __restrict__ root, const float* __restrict__ bias,
                                const int* __restrict__ batch, float* __restrict__ hg, int N){
    int m = threadIdx.x;
    int n = blockIdx.x * 4 + threadIdx.y;
    if (n >= N) return;
    float acc = agg[(size_t)n * 64 + m] + bias[m];
    const float* row = hx + (size_t)n * 64;
    #pragma unroll 8
    for (int k = 0; k < 64; ++k) acc += row[k] * root[k * 64 + m];
    atomicAdd(&hg[batch[n] * 64 + m], lrelu(acc));
}

__global__ void head_kernel(const float* __restrict__ hg, const float* __restrict__ fc1w,
                            const float* __restrict__ fc1b, const float* __restrict__ fc2w,
                            const float* __restrict__ fc2b, float* __restrict__ out){
    int g = threadIdx.x;                       // 0..63
    const float* row = hg + g * 64;
    float h1[32];
    #pragma unroll
    for (int j = 0; j < 32; ++j){
        float a = fc1b[j];
        #pragma unroll 8
        for (int i = 0; i < 64; ++i) a += row[i] * fc1w[i * 32 + j];
        h1[j] = lrelu(a);
    }
    float o = fc2b[0];
    #pragma unroll
    for (int j = 0; j < 32; ++j) o += h1[j] * fc2w[j];
    out[g] = o;
}

extern "C" void kernel_launch(void* const* d_in, const int* in_sizes, int n_in,
                              void* d_out, int out_size, void* d_ws, size_t ws_size,
                              hipStream_t stream){
    const float* x      = (const float*)d_in[0];
    const int*   ei     = (const int*)  d_in[1];
    const float* ea     = (const float*)d_in[2];
    const int*   batch  = (const int*)  d_in[3];
    const float* nfc_w  = (const float*)d_in[4];
    const float* nfc_b  = (const float*)d_in[5];
    const float* e1w1   = (const float*)d_in[6];
    const float* e1b1   = (const float*)d_in[7];
    const float* e1w2   = (const float*)d_in[8];
    const float* e1b2   = (const float*)d_in[9];
    const float* g1root = (const float*)d_in[10];
    const float* g1bias = (const float*)d_in[11];
    const float* e2w1   = (const float*)d_in[12];
    const float* e2b1   = (const float*)d_in[13];
    const float* e2w2   = (const float*)d_in[14];
    const float* e2b2   = (const float*)d_in[15];
    const float* g2root = (const float*)d_in[16];
    const float* g2bias = (const float*)d_in[17];
    const float* fc1w   = (const float*)d_in[18];
    const float* fc1b   = (const float*)d_in[19];
    const float* fc2w   = (const float*)d_in[20];
    const float* fc2b   = (const float*)d_in[21];
    float* out = (float*)d_out;

    const int* src = ei;
    const int* dst = ei + N_EDGES;

    // workspace carve-up
    char* ws = (char*)d_ws;
    float* hx1 = (float*)ws;               ws += (size_t)N_NODES * 64 * 4;
    float* hx2 = (float*)ws;               ws += (size_t)N_NODES * 64 * 4;
    unsigned short* tp = (unsigned short*)ws; ws += (size_t)N_EDGES * 64 * 2;  // 8.2 MB bf16, CSR order
    float* hb2 = (float*)ws;               ws += (size_t)N_NODES * 64 * 4;
    float* agg = (float*)ws;               ws += (size_t)N_NODES * 64 * 4;
    float* hg  = (float*)ws;               ws += (size_t)N_GRAPHS * 64 * 4;
    unsigned short* w2t1 = (unsigned short*)ws; ws += (size_t)64 * 64 * 64 * 2;
    unsigned short* w2t2 = (unsigned short*)ws; ws += (size_t)64 * 64 * 64 * 2;
    int* counts = (int*)ws;                ws += (size_t)10240 * 4;
    int* cursor = (int*)ws;                ws += (size_t)10240 * 4;
    int* rowptr = (int*)ws;                ws += (size_t)10240 * 4;
    int* eidx   = (int*)ws;                ws += (size_t)N_EDGES * 4;
    int* dsts   = (int*)ws;                ws += (size_t)N_EDGES * 4;

    dim3 blk(64, 4);
    dim3 fgrid(FB_NBX, 8);

    // preamble
    hipMemsetAsync(counts, 0, (size_t)N_NODES * 4, stream);
    pre_kernel<<<PRE_NFC + PRE_W2C + PRE_CNT, 256, 0, stream>>>(
        x, nfc_w, nfc_b, hx1, e1w2, w2t1, e2w2, w2t2, src, counts);
    csr_scan_kernel<<<1, 256, 0, stream>>>(counts, rowptr, cursor);
    csr_scatter_kernel<<<N_EDGES / 256, 256, 0, stream>>>(src, dst, rowptr, cursor, eidx, dsts);

    // ---------- layer 1 ----------
    layerB_kernel<0><<<LB_NT + LB_NH, 256, 0, stream>>>(
        ea, eidx, e1w1, e1b1, tp, hx1, e1b2, hb2, agg, nullptr);
    fused_gmat_msg_kernel<<<fgrid, 256, 0, stream>>>(hx1, w2t1, tp, hb2, rowptr, dsts, agg);
    combine_kernel<<<N_NODES / 4, blk, 0, stream>>>(agg, hx1, g1root, g1bias, hx2, N_NODES);

    // ---------- layer 2 ----------
    layerB_kernel<1><<<LB_NT + LB_NH + 1, 256, 0, stream>>>(
        ea, eidx, e2w1, e2b1, tp, hx2, e2b2, hb2, agg, hg);
    fused_gmat_msg_kernel<<<fgrid, 256, 0, stream>>>(hx2, w2t2, tp, hb2, rowptr, dsts, agg);
    combine2_kernel<<<N_NODES / 4, blk, 0, stream>>>(agg, hx2, g2root, g2bias, batch, hg, N_NODES);

    // head
    head_kernel<<<1, 64, 0, stream>>>(hg, fc1w, fc1b, fc2w, fc2b, out);
}

// Round 9
// 254.212 us; speedup vs baseline: 2.2620x; 2.2620x over previous
//
#include <hip/hip_runtime.h>
#include <hip/hip_bf16.h>

#define N_NODES  10000
#define N_EDGES  64000
#define N_GRAPHS 64
#define HID      64

typedef __attribute__((ext_vector_type(8))) short short8;
typedef __attribute__((ext_vector_type(4))) float f32x4;

__device__ __forceinline__ float lrelu(float v){ return v > 0.f ? v : 0.01f*v; }

__device__ __forceinline__ unsigned short f2bf(float f){
    union { float f; unsigned u; } v; v.f = f;
    unsigned r = v.u + 0x7fff + ((v.u >> 16) & 1);
    return (unsigned short)(r >> 16);
}
__device__ __forceinline__ float bf2f(unsigned short s){
    union { unsigned u; float f; } v; v.u = ((unsigned)s) << 16;
    return v.f;
}

// ---------------- preamble: nodeFC | w2conv(x2) | w1t/b2t transposes | csr_count ----------
#define PRE_NFC 2500
#define PRE_W2C 128
#define PRE_TR  4
#define PRE_CNT 250
__global__ void __launch_bounds__(256) pre_kernel(
        const float* __restrict__ x, const float* __restrict__ nfc_w, const float* __restrict__ nfc_b,
        float* __restrict__ hx1,
        const float* __restrict__ e1w2, unsigned short* __restrict__ w2t1,
        const float* __restrict__ e2w2, unsigned short* __restrict__ w2t2,
        const float* __restrict__ e1w1, unsigned short* __restrict__ w1t1,
        const float* __restrict__ e2w1, unsigned short* __restrict__ w1t2,
        const float* __restrict__ e1b2, unsigned short* __restrict__ b2t1,
        const float* __restrict__ e2b2, unsigned short* __restrict__ b2t2,
        const int* __restrict__ src, int* __restrict__ counts){
    __shared__ float tile[64][65];
    int b = blockIdx.x, tid = threadIdx.x;
    if (b < PRE_NFC){
        int m = tid & 63, n = b * 4 + (tid >> 6);
        float acc = nfc_b[m];
        const float* row = x + (size_t)n * 128;
        #pragma unroll 8
        for (int k = 0; k < 128; ++k) acc += row[k] * nfc_w[k * 64 + m];
        hx1[(size_t)n * 64 + m] = lrelu(acc);
    } else if (b < PRE_NFC + PRE_W2C){
        int bb = b - PRE_NFC;
        int k = bb & 63;
        const float* srcw = ((bb < 64) ? e1w2 : e2w2) + (size_t)k * 4096;
        unsigned short* dstw = (bb < 64) ? w2t1 : w2t2;
        for (int idx = tid; idx < 4096; idx += 256) tile[idx >> 6][idx & 63] = srcw[idx];
        __syncthreads();
        for (int idx = tid; idx < 4096; idx += 256){
            int o = idx >> 6, i = idx & 63;
            dstw[((size_t)(k * 64 + o) << 6) + i] = f2bf(tile[i][o]);
        }
    } else if (b < PRE_NFC + PRE_W2C + PRE_TR){
        int bb = b - PRE_NFC - PRE_W2C;
        if (bb < 2){
            const float* w1 = bb ? e2w1 : e1w1;           // [32,64]
            unsigned short* w1t = bb ? w1t2 : w1t1;       // [64][32]
            for (int idx = tid; idx < 2048; idx += 256){
                int o = idx >> 5, k = idx & 31;
                w1t[idx] = f2bf(w1[k * 64 + o]);
            }
        } else {
            const float* b2 = (bb == 3) ? e2b2 : e1b2;    // [64,64] (i,o)
            unsigned short* b2t = (bb == 3) ? b2t2 : b2t1;// [64][64] (o,i)
            for (int idx = tid; idx < 4096; idx += 256){
                int o = idx >> 6, i = idx & 63;
                b2t[idx] = f2bf(b2[i * 64 + o]);
            }
        }
    } else {
        int e = (b - PRE_NFC - PRE_W2C - PRE_TR) * 256 + tid;
        if (e < N_EDGES) atomicAdd(&counts[src[e]], 1);
    }
}

// scan rowptr from counts; also zero the scatter cursor
__global__ void csr_scan_kernel(const int* __restrict__ counts, int* __restrict__ rowptr,
                                int* __restrict__ cursor){
    __shared__ int part[256];
    int tid = threadIdx.x;
    const int CH = (N_NODES + 255) / 256;      // 40
    int base = tid * CH, s = 0;
    for (int i = 0; i < CH; ++i){ int idx = base + i; if (idx < N_NODES){ cursor[idx] = 0; s += counts[idx]; } }
    part[tid] = s; __syncthreads();
    for (int off = 1; off < 256; off <<= 1){
        int v = (tid >= off) ? part[tid - off] : 0;
        __syncthreads();
        part[tid] += v;
        __syncthreads();
    }
    int run = part[tid] - s;
    for (int i = 0; i < CH; ++i){ int idx = base + i; if (idx < N_NODES){ rowptr[idx] = run; run += counts[idx]; } }
    if (tid == 255) rowptr[N_NODES] = run;
}

__global__ void csr_scatter_kernel(const int* __restrict__ src, const int* __restrict__ dst,
                                   const int* __restrict__ rowptr, int* __restrict__ cursor,
                                   int* __restrict__ eidx, int* __restrict__ dsts){
    int e = blockIdx.x * 256 + threadIdx.x;
    if (e >= N_EDGES) return;
    int s = src[e];
    int j = rowptr[s] + atomicAdd(&cursor[s], 1);
    eidx[j] = e; dsts[j] = dst[e];
}

// ---------------- per-layer mega-kernel (all MFMA): t-GEMM | hb2+agg0 | gmat | (hg0) -------
#define NBT2 1000                  // 64 edges/block, 16 per wave
#define NBH2 157                   // 64 nodes/block
#define NBG  (157 * 8)             // gmat: bx 157 x by 8
template<int L2FLAG>
__global__ void __launch_bounds__(256) layerA_kernel(
        const float* __restrict__ ea, const int* __restrict__ eidx,
        const unsigned short* __restrict__ w1t, const float* __restrict__ b1,
        unsigned short* __restrict__ tp,
        const float* __restrict__ hx, const unsigned short* __restrict__ b2t,
        float* __restrict__ hb2, float* __restrict__ agg,
        const unsigned short* __restrict__ w2t, unsigned short* __restrict__ G,
        float* __restrict__ hg){
    __shared__ unsigned short stg[64 * 256];   // 32 KB (gmat branch only)
    int b = blockIdx.x, tid = threadIdx.x;
    int wid = tid >> 6, l = tid & 63;
    int m16 = l & 15, grp = l >> 4;

    if (b < NBT2){
        // t[j,out] = bf16(relu(ea[eidx[j]] @ w1 + b1))  via MFMA (K=32), CSR order
        int j = b * 64 + wid * 16 + m16;
        const float* row = ea + (size_t)eidx[j] * 32 + grp * 8;
        float4 f0 = *(const float4*)(row);
        float4 f1 = *(const float4*)(row + 4);
        short8 ef;
        ef[0]=(short)f2bf(f0.x); ef[1]=(short)f2bf(f0.y); ef[2]=(short)f2bf(f0.z); ef[3]=(short)f2bf(f0.w);
        ef[4]=(short)f2bf(f1.x); ef[5]=(short)f2bf(f1.y); ef[6]=(short)f2bf(f1.z); ef[7]=(short)f2bf(f1.w);
        #pragma unroll
        for (int TB = 0; TB < 64; TB += 16){
            short8 wf = *(const short8*)(w1t + (TB + m16) * 32 + grp * 8);
            f32x4 acc = *(const f32x4*)(b1 + TB + grp * 4);   // bias as C-init
            acc = __builtin_amdgcn_mfma_f32_16x16x32_bf16(wf, ef, acc, 0, 0, 0);
            unsigned p0 = (unsigned)f2bf(fmaxf(acc[0], 0.f)) | ((unsigned)f2bf(fmaxf(acc[1], 0.f)) << 16);
            unsigned p1 = (unsigned)f2bf(fmaxf(acc[2], 0.f)) | ((unsigned)f2bf(fmaxf(acc[3], 0.f)) << 16);
            uint2 pk; pk.x = p0; pk.y = p1;
            *(uint2*)(tp + ((size_t)j << 6) + TB + grp * 4) = pk;
        }
    } else if (b < NBT2 + NBH2){
        // hb2[n,out] = hx[n] @ b2m  via MFMA (K=64); also zero agg rows
        int bb = b - NBT2;
        int node = bb * 64 + wid * 16 + m16;
        short8 h0 = {0,0,0,0,0,0,0,0}, h1 = {0,0,0,0,0,0,0,0};
        if (node < N_NODES){
            const float* hp = hx + ((size_t)node << 6) + grp * 8;
            float4 f0 = *(const float4*)(hp);
            float4 f1 = *(const float4*)(hp + 4);
            float4 f2 = *(const float4*)(hp + 32);
            float4 f3 = *(const float4*)(hp + 36);
            h0[0]=(short)f2bf(f0.x); h0[1]=(short)f2bf(f0.y); h0[2]=(short)f2bf(f0.z); h0[3]=(short)f2bf(f0.w);
            h0[4]=(short)f2bf(f1.x); h0[5]=(short)f2bf(f1.y); h0[6]=(short)f2bf(f1.z); h0[7]=(short)f2bf(f1.w);
            h1[0]=(short)f2bf(f2.x); h1[1]=(short)f2bf(f2.y); h1[2]=(short)f2bf(f2.z); h1[3]=(short)f2bf(f2.w);
            h1[4]=(short)f2bf(f3.x); h1[5]=(short)f2bf(f3.y); h1[6]=(short)f2bf(f3.z); h1[7]=(short)f2bf(f3.w);
        }
        #pragma unroll
        for (int TB = 0; TB < 64; TB += 16){
            short8 c0 = *(const short8*)(b2t + (TB + m16) * 64 + grp * 8);
            short8 c1 = *(const short8*)(b2t + (TB + m16) * 64 + 32 + grp * 8);
            f32x4 acc = {0.f, 0.f, 0.f, 0.f};
            acc = __builtin_amdgcn_mfma_f32_16x16x32_bf16(c0, h0, acc, 0, 0, 0);
            acc = __builtin_amdgcn_mfma_f32_16x16x32_bf16(c1, h1, acc, 0, 0, 0);
            if (node < N_NODES) *(f32x4*)(hb2 + ((size_t)node << 6) + TB + grp * 4) = acc;
        }
        f32x4 z = {0.f, 0.f, 0.f, 0.f};
        #pragma unroll
        for (int q = 0; q < 4; ++q){
            int chunk = q * 256 + tid;                      // 1024 f32x4 chunks
            int n = bb * 64 + (chunk >> 4), c = (chunk & 15) * 4;
            if (n < N_NODES) *(f32x4*)(agg + ((size_t)n << 6) + c) = z;
        }
    } else if (b < NBT2 + NBH2 + NBG){
        // gmat: G[n, col] = sum_i hx[n,i] * w2t[col, i] (swapped-operand MFMA, LDS-staged)
        int g = b - NBT2 - NBH2;
        int bx = g >> 3, by = g & 7;
        int n0 = bx * 64;
        int cb = by * 512;

        short8 bf0[4], bf1[4];
        #pragma unroll
        for (int ng = 0; ng < 4; ++ng){
            int node = n0 + ng * 16 + m16;
            short8 b0 = {0,0,0,0,0,0,0,0}, b1v = {0,0,0,0,0,0,0,0};
            if (node < N_NODES){
                const float* hp = hx + ((size_t)node << 6) + grp * 8;
                float4 f0 = *(const float4*)(hp);
                float4 f1 = *(const float4*)(hp + 4);
                float4 f2 = *(const float4*)(hp + 32);
                float4 f3 = *(const float4*)(hp + 36);
                b0[0]=(short)f2bf(f0.x); b0[1]=(short)f2bf(f0.y); b0[2]=(short)f2bf(f0.z); b0[3]=(short)f2bf(f0.w);
                b0[4]=(short)f2bf(f1.x); b0[5]=(short)f2bf(f1.y); b0[6]=(short)f2bf(f1.z); b0[7]=(short)f2bf(f1.w);
                b1v[0]=(short)f2bf(f2.x); b1v[1]=(short)f2bf(f2.y); b1v[2]=(short)f2bf(f2.z); b1v[3]=(short)f2bf(f2.w);
                b1v[4]=(short)f2bf(f3.x); b1v[5]=(short)f2bf(f3.y); b1v[6]=(short)f2bf(f3.z); b1v[7]=(short)f2bf(f3.w);
            }
            bf0[ng] = b0; bf1[ng] = b1v;
        }

        for (int h = 0; h < 2; ++h){
            #pragma unroll
            for (int tt = 0; tt < 4; ++tt){
                int t = h * 4 + tt;
                int TB = cb + t * 64 + wid * 16;
                const unsigned short* ap = w2t + ((size_t)(TB + m16) << 6) + grp * 8;
                short8 a0 = *(const short8*)ap;
                short8 a1 = *(const short8*)(ap + 32);
                int inrow = (tt * 128 + wid * 32 + grp * 8) ^ ((m16 & 7) << 4);
                #pragma unroll
                for (int ng = 0; ng < 4; ++ng){
                    f32x4 acc = {0.f, 0.f, 0.f, 0.f};
                    acc = __builtin_amdgcn_mfma_f32_16x16x32_bf16(a0, bf0[ng], acc, 0, 0, 0);
                    acc = __builtin_amdgcn_mfma_f32_16x16x32_bf16(a1, bf1[ng], acc, 0, 0, 0);
                    unsigned p0 = (unsigned)f2bf(acc[0]) | ((unsigned)f2bf(acc[1]) << 16);
                    unsigned p1 = (unsigned)f2bf(acc[2]) | ((unsigned)f2bf(acc[3]) << 16);
                    int row = ng * 16 + m16;
                    uint2 pk; pk.x = p0; pk.y = p1;
                    *(uint2*)((char*)stg + row * 512 + inrow) = pk;
                }
            }
            __syncthreads();
            #pragma unroll
            for (int s = 0; s < 8; ++s){
                int ci = s * 256 + tid;
                int row = ci >> 5;
                int node = n0 + row;
                uint4 v = *(uint4*)((char*)stg + row * 512 + (((ci & 31) * 16) ^ ((row & 7) << 4)));
                if (node < N_NODES)
                    *(uint4*)(G + ((size_t)node << 12) + cb + h * 256 + (ci & 31) * 8) = v;
            }
            __syncthreads();
        }
    } else if (L2FLAG){
        for (int i = tid; i < N_GRAPHS * 64; i += 256) hg[i] = 0.f;
    }
}

// ---------------- msg, grouped by src: G row streamed once; tp is bf16 CSR-ordered ----------
__global__ void __launch_bounds__(64) msg_csr_kernel(
        const unsigned short* __restrict__ tp, const unsigned short* __restrict__ G,
        const float* __restrict__ hb2, const int* __restrict__ rowptr,
        const int* __restrict__ dsts, float* __restrict__ agg){
    int s = blockIdx.x;
    int o = threadIdx.x;
    __shared__ unsigned short gl[4096];
    __shared__ unsigned short ts[64] __attribute__((aligned(16)));
    int r0 = rowptr[s], r1 = rowptr[s + 1];
    if (r0 == r1) return;                      // isolated node: agg row stays 0
    const short8* gsrc = (const short8*)(G + ((size_t)s << 12));
    short8* gld = (short8*)gl;
    #pragma unroll
    for (int i = 0; i < 8; ++i) gld[i * 64 + o] = gsrc[i * 64 + o];
    float g[64];
    #pragma unroll
    for (int k = 0; k < 64; ++k) g[k] = bf2f(gl[k * 64 + o]);
    float hb = hb2[((size_t)s << 6) + o];
    for (int j = r0; j < r1; ++j){
        ts[o] = tp[((size_t)j << 6) + o];
        float acc = hb;
        #pragma unroll
        for (int k8 = 0; k8 < 8; ++k8){
            short8 tv = *(const short8*)&ts[k8 * 8];
            #pragma unroll
            for (int u = 0; u < 8; ++u) acc += bf2f((unsigned short)tv[u]) * g[k8 * 8 + u];
        }
        atomicAdd(&agg[((size_t)dsts[j] << 6) + o], acc);
    }
}

// out[n,o] = lrelu(agg[n,o] + hx[n] @ root + bias)
__global__ void combine_kernel(const float* __restrict__ agg, const float* __restrict__ hx,
                               const float* __restrict__ root, const float* __restrict__ bias,
                               float* __restrict__ out, int N){
    int m = threadIdx.x;
    int n = blockIdx.x * 4 + threadIdx.y;
    if (n >= N) return;
    float acc = agg[(size_t)n * 64 + m] + bias[m];
    const float* row = hx + (size_t)n * 64;
    #pragma unroll 8
    for (int k = 0; k < 64; ++k) acc += row[k] * root[k * 64 + m];
    out[(size_t)n * 64 + m] = lrelu(acc);
}

// layer-2 combine fused with global_add_pool
__global__ void combine2_kernel(const float* __restrict__ agg, const float* __restrict__ hx,
                                const float* __restrict__ root, const float* __restrict__ bias,
                                const int* __restrict__ batch, float* __restrict__ hg, int N){
    int m = threadIdx.x;
    int n = blockIdx.x * 4 + threadIdx.y;
    if (n >= N) return;
    float acc = agg[(size_t)n * 64 + m] + bias[m];
    const float* row = hx + (size_t)n * 64;
    #pragma unroll 8
    for (int k = 0; k < 64; ++k) acc += row[k] * root[k * 64 + m];
    atomicAdd(&hg[batch[n] * 64 + m], lrelu(acc));
}

__global__ void head_kernel(const float* __restrict__ hg, const float* __restrict__ fc1w,
                            const float* __restrict__ fc1b, const float* __restrict__ fc2w,
                            const float* __restrict__ fc2b, float* __restrict__ out){
    int g = threadIdx.x;                       // 0..63
    const float* row = hg + g * 64;
    float h1[32];
    #pragma unroll
    for (int j = 0; j < 32; ++j){
        float a = fc1b[j];
        #pragma unroll 8
        for (int i = 0; i < 64; ++i) a += row[i] * fc1w[i * 32 + j];
        h1[j] = lrelu(a);
    }
    float o = fc2b[0];
    #pragma unroll
    for (int j = 0; j < 32; ++j) o += h1[j] * fc2w[j];
    out[g] = o;
}

extern "C" void kernel_launch(void* const* d_in, const int* in_sizes, int n_in,
                              void* d_out, int out_size, void* d_ws, size_t ws_size,
                              hipStream_t stream){
    const float* x      = (const float*)d_in[0];
    const int*   ei     = (const int*)  d_in[1];
    const float* ea     = (const float*)d_in[2];
    const int*   batch  = (const int*)  d_in[3];
    const float* nfc_w  = (const float*)d_in[4];
    const float* nfc_b  = (const float*)d_in[5];
    const float* e1w1   = (const float*)d_in[6];
    const float* e1b1   = (const float*)d_in[7];
    const float* e1w2   = (const float*)d_in[8];
    const float* e1b2   = (const float*)d_in[9];
    const float* g1root = (const float*)d_in[10];
    const float* g1bias = (const float*)d_in[11];
    const float* e2w1   = (const float*)d_in[12];
    const float* e2b1   = (const float*)d_in[13];
    const float* e2w2   = (const float*)d_in[14];
    const float* e2b2   = (const float*)d_in[15];
    const float* g2root = (const float*)d_in[16];
    const float* g2bias = (const float*)d_in[17];
    const float* fc1w   = (const float*)d_in[18];
    const float* fc1b   = (const float*)d_in[19];
    const float* fc2w   = (const float*)d_in[20];
    const float* fc2b   = (const float*)d_in[21];
    float* out = (float*)d_out;

    const int* src = ei;
    const int* dst = ei + N_EDGES;

    // workspace carve-up
    char* ws = (char*)d_ws;
    float* hx1 = (float*)ws;               ws += (size_t)N_NODES * 64 * 4;
    float* hx2 = (float*)ws;               ws += (size_t)N_NODES * 64 * 4;
    unsigned short* tp = (unsigned short*)ws; ws += (size_t)N_EDGES * 64 * 2;  // bf16, CSR order
    float* hb2 = (float*)ws;               ws += (size_t)N_NODES * 64 * 4;
    float* agg = (float*)ws;               ws += (size_t)N_NODES * 64 * 4;
    float* hg  = (float*)ws;               ws += (size_t)N_GRAPHS * 64 * 4;
    unsigned short* w2t1 = (unsigned short*)ws; ws += (size_t)64 * 64 * 64 * 2;
    unsigned short* w2t2 = (unsigned short*)ws; ws += (size_t)64 * 64 * 64 * 2;
    unsigned short* w1t1 = (unsigned short*)ws; ws += (size_t)2048 * 2;
    unsigned short* w1t2 = (unsigned short*)ws; ws += (size_t)2048 * 2;
    unsigned short* b2t1 = (unsigned short*)ws; ws += (size_t)4096 * 2;
    unsigned short* b2t2 = (unsigned short*)ws; ws += (size_t)4096 * 2;
    int* counts = (int*)ws;                ws += (size_t)10240 * 4;
    int* cursor = (int*)ws;                ws += (size_t)10240 * 4;
    int* rowptr = (int*)ws;                ws += (size_t)10240 * 4;
    int* eidx   = (int*)ws;                ws += (size_t)N_EDGES * 4;
    int* dsts   = (int*)ws;                ws += (size_t)N_EDGES * 4;
    unsigned short* G = (unsigned short*)ws;  // 82 MB

    dim3 blk(64, 4);

    // preamble
    hipMemsetAsync(counts, 0, (size_t)N_NODES * 4, stream);
    pre_kernel<<<PRE_NFC + PRE_W2C + PRE_TR + PRE_CNT, 256, 0, stream>>>(
        x, nfc_w, nfc_b, hx1, e1w2, w2t1, e2w2, w2t2,
        e1w1, w1t1, e2w1, w1t2, e1b2, b2t1, e2b2, b2t2, src, counts);
    csr_scan_kernel<<<1, 256, 0, stream>>>(counts, rowptr, cursor);
    csr_scatter_kernel<<<N_EDGES / 256, 256, 0, stream>>>(src, dst, rowptr, cursor, eidx, dsts);

    // ---------- layer 1 ----------
    layerA_kernel<0><<<NBT2 + NBH2 + NBG, 256, 0, stream>>>(
        ea, eidx, w1t1, e1b1, tp, hx1, b2t1, hb2, agg, w2t1, G, nullptr);
    msg_csr_kernel<<<N_NODES, 64, 0, stream>>>(tp, G, hb2, rowptr, dsts, agg);
    combine_kernel<<<N_NODES / 4, blk, 0, stream>>>(agg, hx1, g1root, g1bias, hx2, N_NODES);

    // ---------- layer 2 ----------
    layerA_kernel<1><<<NBT2 + NBH2 + NBG + 1, 256, 0, stream>>>(
        ea, eidx, w1t2, e2b1, tp, hx2, b2t2, hb2, agg, w2t2, G, hg);
    msg_csr_kernel<<<N_NODES, 64, 0, stream>>>(tp, G, hb2, rowptr, dsts, agg);
    combine2_kernel<<<N_NODES / 4, blk, 0, stream>>>(agg, hx2, g2root, g2bias, batch, hg, N_NODES);

    // head
    head_kernel<<<1, 64, 0, stream>>>(hg, fc1w, fc1b, fc2w, fc2b, out);
}